// Round 2
// 398.549 us; speedup vs baseline: 1.0168x; 1.0168x over previous
//
#include <hip/hip_runtime.h>
#include <math.h>

// GraphAttentionLayer:
//   Wh = X @ W ; f = Wh @ a1 ; g = Wh @ a2
//   attention = softmax(leaky_relu(f[:,None] + g[None,:]), axis=1)
// Reassociated: f = X @ (W@a1), g = X @ (W@a2).  adj is unused by the reference.
// leaky_relu is monotone => row max = lrelu(f_i + max(g)).

static constexpr float ALPHA = 0.2f;
static constexpr int N    = 8192;
static constexpr int FIN  = 512;
static constexpr int FOUT = 256;

typedef float v4f __attribute__((ext_vector_type(4)));

__device__ __forceinline__ float lrelu(float x) {
    // for 0<ALPHA<1: lrelu(x) == max(x, ALPHA*x)  (x>=0: x; x<0: ALPHA*x > x)
    return fmaxf(x, ALPHA * x);
}

// ---------------- Kernel A: wa1[k] = sum_j W[k,j]*a[j]; wa2[k] = sum_j W[k,j]*a[FOUT+j]
// grid = FIN blocks x 64 threads (one wave per W row)
__global__ void k_wa(const float* __restrict__ W, const float* __restrict__ a,
                     float* __restrict__ wa1, float* __restrict__ wa2) {
    const int k    = blockIdx.x;
    const int lane = threadIdx.x;
    const float* row = W + (size_t)k * FOUT;
    float s1 = 0.0f, s2 = 0.0f;
    for (int j = lane; j < FOUT; j += 64) {
        const float w = row[j];
        s1 += w * a[j];
        s2 += w * a[FOUT + j];
    }
    #pragma unroll
    for (int off = 32; off > 0; off >>= 1) {
        s1 += __shfl_down(s1, off, 64);
        s2 += __shfl_down(s2, off, 64);
    }
    if (lane == 0) { wa1[k] = s1; wa2[k] = s2; }
}

// ---------------- Kernel B: f[i] = dot(X[i,:], wa1); g[i] = dot(X[i,:], wa2)
// one wave per row; 4 waves/block
__global__ __launch_bounds__(256) void k_fg(const float* __restrict__ X,
                                            const float* __restrict__ wa1,
                                            const float* __restrict__ wa2,
                                            float* __restrict__ f,
                                            float* __restrict__ g) {
    const int gid  = blockIdx.x * blockDim.x + threadIdx.x;
    const int row  = gid >> 6;
    const int lane = threadIdx.x & 63;
    if (row >= N) return;
    const float4* x4  = (const float4*)(X + (size_t)row * FIN);
    const float4* w14 = (const float4*)wa1;
    const float4* w24 = (const float4*)wa2;
    float s1 = 0.0f, s2 = 0.0f;
    #pragma unroll
    for (int k4 = lane; k4 < (FIN >> 2); k4 += 64) {
        const float4 v  = x4[k4];
        const float4 w1 = w14[k4];
        const float4 w2 = w24[k4];
        s1 += v.x*w1.x + v.y*w1.y + v.z*w1.z + v.w*w1.w;
        s2 += v.x*w2.x + v.y*w2.y + v.z*w2.z + v.w*w2.w;
    }
    #pragma unroll
    for (int off = 32; off > 0; off >>= 1) {
        s1 += __shfl_down(s1, off, 64);
        s2 += __shfl_down(s2, off, 64);
    }
    if (lane == 0) { f[row] = s1; g[row] = s2; }
}

// ---------------- Kernel C: gmax = max(g) ; single block, 256 threads, float4
__global__ __launch_bounds__(256) void k_gmax(const float* __restrict__ g,
                                              float* __restrict__ gmax) {
    __shared__ float sm[4];
    const float4* g4 = (const float4*)g;
    float m = -INFINITY;
    #pragma unroll
    for (int j = threadIdx.x; j < (N >> 2); j += 256) {  // 8 iters
        const float4 v = g4[j];
        m = fmaxf(fmaxf(m, v.x), fmaxf(v.y, fmaxf(v.z, v.w)));
    }
    #pragma unroll
    for (int off = 32; off > 0; off >>= 1) m = fmaxf(m, __shfl_down(m, off, 64));
    if ((threadIdx.x & 63) == 0) sm[threadIdx.x >> 6] = m;
    __syncthreads();
    if (threadIdx.x == 0) {
        *gmax = fmaxf(fmaxf(sm[0], sm[1]), fmaxf(sm[2], sm[3]));
    }
}

// ---------------- Kernel D: per-row softmax of lrelu(f_i + g_j)
// block per row, 256 threads. Each thread owns exactly 8 float4 (32 cols):
// exp values are computed ONCE and cached in 32 VGPRs across the reduction,
// then scaled and written with nontemporal stores (output is never re-read).
__global__ __launch_bounds__(256) void k_attn(const float* __restrict__ f,
                                              const float* __restrict__ g,
                                              const float* __restrict__ gmaxp,
                                              float* __restrict__ out) {
    const int i = blockIdx.x;
    const float fi = f[i];
    const float m  = lrelu(fi + *gmaxp);

    const float4* g4   = (const float4*)g;
    v4f*          out4 = (v4f*)(out + (size_t)i * N);
    constexpr int n4 = N >> 2;        // 2048
    constexpr int PT = n4 / 256;      // 8 float4 per thread = 32 VGPRs

    float4 p[PT];
    float sum = 0.0f;
    #pragma unroll
    for (int t = 0; t < PT; ++t) {
        const int j = threadIdx.x + t * 256;
        const float4 gv = g4[j];
        float4 e;
        e.x = __expf(lrelu(fi + gv.x) - m);
        e.y = __expf(lrelu(fi + gv.y) - m);
        e.z = __expf(lrelu(fi + gv.z) - m);
        e.w = __expf(lrelu(fi + gv.w) - m);
        sum += (e.x + e.y) + (e.z + e.w);
        p[t] = e;
    }

    __shared__ float sm[4];
    #pragma unroll
    for (int off = 32; off > 0; off >>= 1) sum += __shfl_down(sum, off, 64);
    if ((threadIdx.x & 63) == 0) sm[threadIdx.x >> 6] = sum;
    __syncthreads();
    const float total = (sm[0] + sm[1]) + (sm[2] + sm[3]);
    const float inv = 1.0f / total;

    #pragma unroll
    for (int t = 0; t < PT; ++t) {
        const int j = threadIdx.x + t * 256;
        v4f o;
        o.x = p[t].x * inv;
        o.y = p[t].y * inv;
        o.z = p[t].z * inv;
        o.w = p[t].w * inv;
        __builtin_nontemporal_store(o, &out4[j]);
    }
}

extern "C" void kernel_launch(void* const* d_in, const int* in_sizes, int n_in,
                              void* d_out, int out_size, void* d_ws, size_t ws_size,
                              hipStream_t stream) {
    const float* X = (const float*)d_in[0];   // (N, FIN)
    // d_in[1] = adj — unused by the reference computation
    const float* W = (const float*)d_in[2];   // (FIN, FOUT)
    const float* a = (const float*)d_in[3];   // (2*FOUT, 1)
    float* out = (float*)d_out;               // (N, N)

    float* ws   = (float*)d_ws;
    float* wa1  = ws;                 // FIN
    float* wa2  = ws + FIN;           // FIN
    float* f    = ws + 2 * FIN;       // N
    float* g    = ws + 2 * FIN + N;   // N
    float* gmax = ws + 2 * FIN + 2*N; // 1

    k_wa  <<<FIN, 64, 0, stream>>>(W, a, wa1, wa2);
    k_fg  <<<(N * 64 + 255) / 256, 256, 0, stream>>>(X, wa1, wa2, f, g);
    k_gmax<<<1, 256, 0, stream>>>(g, gmax);
    k_attn<<<N, 256, 0, stream>>>(f, g, gmax, out);
}